// Round 6
// baseline (18836.577 us; speedup 1.0000x reference)
//
#include <hip/hip_runtime.h>
#include <math.h>

// Problem dims
#define B_  32
#define S_  512
#define H_  1024
#define V_  8192
#define G4_ 4096   // 4H
#define H2_ 2048   // 2H

// ---------------------------------------------------------------------------
// Generic fp32 GEMM:  C[m,n] = act( sum_k Arow(m,k) * B(n,k or k,n) + bias )
// Arow(m,k) = k < K1 ? A1[m*K1+k] : A2[m*K2+(k-K1)]   (concat rows)
// TRANSB=1: B is [N x K] row-major (NT, dot of rows). TRANSB=0: B is [K x N].
// Batched via blockIdx.z with strides sA (A1 only), sB, sC.
// Tile 128x128, BK=16, 256 threads, 8x8 per thread.
// ---------------------------------------------------------------------------
template<int TRANSB>
__global__ __launch_bounds__(256)
void sgemm_kernel(const float* __restrict__ A1, const float* __restrict__ A2,
                  const float* __restrict__ Bm,
                  const float* __restrict__ bias1, const float* __restrict__ bias2,
                  float* __restrict__ C,
                  int M, int N, int K1, int K2, int ldb, int ldc,
                  long sA, long sB, long sC, int act)
{
    __shared__ float As[16][132];
    __shared__ float Bs[16][132];
    const int tid = threadIdx.x;
    const int n0 = blockIdx.x * 128;
    const int m0 = blockIdx.y * 128;
    const int z  = blockIdx.z;
    const float* A1z = A1 + (long)z * sA;
    const float* A2z = A2;                 // concat-A is never batched here
    const float* Bz  = Bm + (long)z * sB;
    float*       Cz  = C  + (long)z * sC;

    const int K  = K1 + K2;
    const int tx = tid & 15, ty = tid >> 4;

    float acc[8][8];
#pragma unroll
    for (int i = 0; i < 8; i++)
#pragma unroll
        for (int j = 0; j < 8; j++) acc[i][j] = 0.f;

    for (int k0 = 0; k0 < K; k0 += 16) {
        // ---- A tile: As[kk][mm] = Arow(m0+mm, k0+kk)
#pragma unroll
        for (int q = 0; q < 2; q++) {
            int L   = q * 256 + tid;
            int mm  = L >> 2;
            int kk4 = (L & 3) << 2;
            int gk  = k0 + kk4;
            float4 v;
            if (gk < K1) v = *(const float4*)(A1z + (long)(m0 + mm) * K1 + gk);
            else         v = *(const float4*)(A2z + (long)(m0 + mm) * K2 + (gk - K1));
            As[kk4 + 0][mm] = v.x; As[kk4 + 1][mm] = v.y;
            As[kk4 + 2][mm] = v.z; As[kk4 + 3][mm] = v.w;
        }
        // ---- B tile
        if (TRANSB) {
#pragma unroll
            for (int q = 0; q < 2; q++) {
                int L   = q * 256 + tid;
                int nn  = L >> 2;
                int kk4 = (L & 3) << 2;
                float4 v = *(const float4*)(Bz + (long)(n0 + nn) * ldb + k0 + kk4);
                Bs[kk4 + 0][nn] = v.x; Bs[kk4 + 1][nn] = v.y;
                Bs[kk4 + 2][nn] = v.z; Bs[kk4 + 3][nn] = v.w;
            }
        } else {
#pragma unroll
            for (int q = 0; q < 2; q++) {
                int L   = q * 256 + tid;
                int kk  = L >> 5;
                int nn4 = (L & 31) << 2;
                float4 v = *(const float4*)(Bz + (long)(k0 + kk) * ldb + n0 + nn4);
                *(float4*)&Bs[kk][nn4] = v;
            }
        }
        __syncthreads();
#pragma unroll
        for (int kk = 0; kk < 16; kk++) {
            float a[8], b[8];
            *(float4*)&a[0] = *(const float4*)&As[kk][ty * 8];
            *(float4*)&a[4] = *(const float4*)&As[kk][ty * 8 + 4];
            *(float4*)&b[0] = *(const float4*)&Bs[kk][tx * 8];
            *(float4*)&b[4] = *(const float4*)&Bs[kk][tx * 8 + 4];
#pragma unroll
            for (int i = 0; i < 8; i++)
#pragma unroll
                for (int j = 0; j < 8; j++)
                    acc[i][j] = fmaf(a[i], b[j], acc[i][j]);
        }
        __syncthreads();
    }
    // ---- epilogue
#pragma unroll
    for (int i = 0; i < 8; i++) {
        long gm = m0 + ty * 8 + i;
#pragma unroll
        for (int j4 = 0; j4 < 2; j4++) {
            int gn = n0 + tx * 8 + j4 * 4;
            float4 v;
            v.x = acc[i][j4 * 4 + 0]; v.y = acc[i][j4 * 4 + 1];
            v.z = acc[i][j4 * 4 + 2]; v.w = acc[i][j4 * 4 + 3];
            if (bias1) { v.x += bias1[gn + 0]; v.y += bias1[gn + 1];
                         v.z += bias1[gn + 2]; v.w += bias1[gn + 3]; }
            if (bias2) { v.x += bias2[gn + 0]; v.y += bias2[gn + 1];
                         v.z += bias2[gn + 2]; v.w += bias2[gn + 3]; }
            if (act == 1) { v.x = tanhf(v.x); v.y = tanhf(v.y);
                            v.z = tanhf(v.z); v.w = tanhf(v.w); }
            *(float4*)(Cz + gm * ldc + gn) = v;
        }
    }
}

// ---------------------------------------------------------------------------
// One LSTM step. 256 blocks x 256 threads. Block bid owns h-columns
// [bid*4, bid*4+4) and the 16 gate rows {g*1024 + bid*4 + jj}.
// W_hh slice is held in registers (64 f/thread) and re-read from L2 each
// launch (per-XCD footprint ~2MB -> L2 resident). h_prev staged via LDS in
// 4 K-chunks of 256. Cross-lane reduce via shfl_xor; cross-wave via LDS.
// ---------------------------------------------------------------------------
__global__ __launch_bounds__(256, 1)
void lstm_step_kernel(const float* __restrict__ gpre, const float* __restrict__ Whh,
                      const float* __restrict__ hprev, long hstride,
                      const float* __restrict__ cprev,
                      float* __restrict__ cnext, float* __restrict__ hall_t,
                      int t)
{
    __shared__ float hs[64 * 132];          // 33.8 KB; reused as reduce scratch
    const int tid = threadIdx.x;
    const int bid = blockIdx.x;
    const int rr  = tid & 3;                // gate index 0..3 (i,f,g,o)
    const int c   = tid >> 2;               // k-sub-chunk 0..63

    // W registers: rows (rr*1024 + bid*4 + m), k = q*256 + c*4 + j
    float wreg[4][16];
#pragma unroll
    for (int m = 0; m < 4; m++) {
        const float* wr = Whh + (long)(rr * 1024 + bid * 4 + m) * 1024;
#pragma unroll
        for (int q = 0; q < 4; q++) {
            float4 v = *(const float4*)(wr + q * 256 + c * 4);
            wreg[m][q * 4 + 0] = v.x; wreg[m][q * 4 + 1] = v.y;
            wreg[m][q * 4 + 2] = v.z; wreg[m][q * 4 + 3] = v.w;
        }
    }

    float acc[4][32];
#pragma unroll
    for (int m = 0; m < 4; m++)
#pragma unroll
        for (int b = 0; b < 32; b++) acc[m][b] = 0.f;

#pragma unroll
    for (int q = 0; q < 4; q++) {
        // stage chunk q: layout hs[g*132 + b*4 + e], g = k-group 0..63
        {
            int g  = tid & 63;
            int bq = tid >> 6;
#pragma unroll
            for (int v4 = 0; v4 < 8; v4++) {
                int b = bq * 8 + v4;
                float4 v = *(const float4*)(hprev + (long)b * hstride + q * 256 + g * 4);
                *(float4*)&hs[g * 132 + b * 4] = v;
            }
        }
        __syncthreads();
#pragma unroll
        for (int b = 0; b < 32; b++) {
            float4 h4 = *(const float4*)&hs[c * 132 + b * 4];
#pragma unroll
            for (int m = 0; m < 4; m++) {
                acc[m][b] = fmaf(wreg[m][q * 4 + 0], h4.x, acc[m][b]);
                acc[m][b] = fmaf(wreg[m][q * 4 + 1], h4.y, acc[m][b]);
                acc[m][b] = fmaf(wreg[m][q * 4 + 2], h4.z, acc[m][b]);
                acc[m][b] = fmaf(wreg[m][q * 4 + 3], h4.w, acc[m][b]);
            }
        }
        __syncthreads();
    }

    // reduce over c_local (lane bits 2..5) within wave
#pragma unroll
    for (int m = 0; m < 4; m++)
#pragma unroll
        for (int b = 0; b < 32; b++) {
            float v = acc[m][b];
            v += __shfl_xor(v, 4);
            v += __shfl_xor(v, 8);
            v += __shfl_xor(v, 16);
            v += __shfl_xor(v, 32);
            acc[m][b] = v;
        }

    // cross-wave partials into LDS (hs is free now)
    int w = tid >> 6;
    if ((tid & 63) < 4) {
        int r2 = tid & 3;
#pragma unroll
        for (int m = 0; m < 4; m++)
#pragma unroll
            for (int b = 0; b < 32; b++)
                hs[(w * 16 + r2 * 4 + m) * 33 + b] = acc[m][b];
    }
    __syncthreads();

    if (tid < 128) {
        int jj = tid >> 5;
        int b  = tid & 31;
        float gv[4];
#pragma unroll
        for (int g = 0; g < 4; g++) {
            int lr = g * 4 + jj;
            float s = hs[(0 * 16 + lr) * 33 + b] + hs[(1 * 16 + lr) * 33 + b]
                    + hs[(2 * 16 + lr) * 33 + b] + hs[(3 * 16 + lr) * 33 + b];
            gv[g] = s + gpre[((long)b * S_ + t) * G4_ + g * H_ + bid * 4 + jj];
        }
        int col = bid * 4 + jj;
        float cp = cprev[b * H_ + col];
        float ig = 1.f / (1.f + expf(-gv[0]));
        float fg = 1.f / (1.f + expf(-gv[1]));
        float gg = tanhf(gv[2]);
        float og = 1.f / (1.f + expf(-gv[3]));
        float cn = fg * cp + ig * gg;
        float hn = og * tanhf(cn);
        cnext[b * H_ + col] = cn;
        hall_t[(long)b * (S_ * H_) + col] = hn;
    }
}

// ---------------------------------------------------------------------------
// reductions
// ---------------------------------------------------------------------------
__device__ __forceinline__ float wave_max(float v) {
    v = fmaxf(v, __shfl_xor(v, 1));  v = fmaxf(v, __shfl_xor(v, 2));
    v = fmaxf(v, __shfl_xor(v, 4));  v = fmaxf(v, __shfl_xor(v, 8));
    v = fmaxf(v, __shfl_xor(v, 16)); v = fmaxf(v, __shfl_xor(v, 32));
    return v;
}
__device__ __forceinline__ float wave_sum(float v) {
    v += __shfl_xor(v, 1);  v += __shfl_xor(v, 2);
    v += __shfl_xor(v, 4);  v += __shfl_xor(v, 8);
    v += __shfl_xor(v, 16); v += __shfl_xor(v, 32);
    return v;
}

// masked softmax over s for one (b,t) row of 512
__global__ __launch_bounds__(256)
void masked_softmax_kernel(float* __restrict__ sc, const int* __restrict__ xs)
{
    __shared__ float red[4];
    int row = blockIdx.x;
    int b   = row >> 9;
    int len = xs[b];
    float* p = sc + (long)row * S_;
    int tid = threadIdx.x;
    float v0 = p[tid];
    float v1 = p[tid + 256];
    v0 = (tid < len) ? v0 : 0.f;       if (v0 == 0.f) v0 = -1e10f;
    v1 = (tid + 256 < len) ? v1 : 0.f; if (v1 == 0.f) v1 = -1e10f;
    float m = wave_max(fmaxf(v0, v1));
    if ((tid & 63) == 0) red[tid >> 6] = m;
    __syncthreads();
    m = fmaxf(fmaxf(red[0], red[1]), fmaxf(red[2], red[3]));
    float e0 = expf(v0 - m), e1 = expf(v1 - m);
    float s = wave_sum(e0 + e1);
    __syncthreads();
    if ((tid & 63) == 0) red[tid >> 6] = s;
    __syncthreads();
    s = red[0] + red[1] + red[2] + red[3];
    float inv = 1.f / s;
    p[tid] = e0 * inv;
    p[tid + 256] = e1 * inv;
}

// in-place log_softmax over V=8192 per row
__global__ __launch_bounds__(256)
void log_softmax_kernel(float* __restrict__ out)
{
    __shared__ float red[4];
    long row = blockIdx.x;
    float* p = out + row * V_;
    int tid = threadIdx.x;
    float x[32];
#pragma unroll
    for (int i = 0; i < 8; i++)
        *(float4*)&x[i * 4] = *(const float4*)(p + i * 1024 + tid * 4);
    float m = -INFINITY;
#pragma unroll
    for (int i = 0; i < 32; i++) m = fmaxf(m, x[i]);
    m = wave_max(m);
    if ((tid & 63) == 0) red[tid >> 6] = m;
    __syncthreads();
    m = fmaxf(fmaxf(red[0], red[1]), fmaxf(red[2], red[3]));
    float s = 0.f;
#pragma unroll
    for (int i = 0; i < 32; i++) s += expf(x[i] - m);
    s = wave_sum(s);
    __syncthreads();
    if ((tid & 63) == 0) red[tid >> 6] = s;
    __syncthreads();
    s = red[0] + red[1] + red[2] + red[3];
    float lse = m + logf(s);
#pragma unroll
    for (int i = 0; i < 8; i++) {
        float4 v;
        v.x = x[i * 4 + 0] - lse; v.y = x[i * 4 + 1] - lse;
        v.z = x[i * 4 + 2] - lse; v.w = x[i * 4 + 3] - lse;
        *(float4*)(p + i * 1024 + tid * 4) = v;
    }
}

// ---------------------------------------------------------------------------
extern "C" void kernel_launch(void* const* d_in, const int* in_sizes, int n_in,
                              void* d_out, int out_size, void* d_ws, size_t ws_size,
                              hipStream_t stream)
{
    const float* enc  = (const float*)d_in[0];
    const float* h0   = (const float*)d_in[1];
    const float* c0   = (const float*)d_in[2];
    const float* cv   = (const float*)d_in[3];
    const float* W_ih = (const float*)d_in[4];
    const float* b_ih = (const float*)d_in[5];
    const float* W_hh = (const float*)d_in[6];
    const float* b_hh = (const float*)d_in[7];
    const float* al1  = (const float*)d_in[8];
    const float* al2  = (const float*)d_in[9];
    const float* l1w  = (const float*)d_in[10];
    const float* l1b  = (const float*)d_in[11];
    const float* l2w  = (const float*)d_in[12];
    const float* l2b  = (const float*)d_in[13];
    const int*   xs   = (const int*)d_in[14];
    float* out = (float*)d_out;

    // ---- scratch carve ----
    // d_out (16384 x 8192 fp32 = 512MB = 134,217,728 floats) is legal scratch
    // until phase 3g overwrites all of it:
    //   gpre    @ out+0          [67,108,864]  ph1 W; ph2 R; dead -> ctxbuf (3d W, 3e R)
    //   qbuf    @ out+67,108,864 [16,777,216]  3a W; 3b R; dead -> ctx2buf (3e W, 3f R)
    //   scoresb @ out+83,886,080 [ 8,388,608]  3b W; 3c RW; 3d R; dead
    //   hall    @ out+92,274,688 [16,777,216]  ph2 W; 3a R, 3e R; dead
    //     (ends at 109,051,904 < 134,217,728; untouched by any other phase)
    // d_ws holds only what must survive 3g's full-d_out overwrite:
    //   t1buf [16,777,216] + cws [32,768]  -> 67.2 MB required
    float* gpre    = out;
    float* qbuf    = out + 67108864;
    float* scoresb = out + 83886080;
    float* hall    = out + 92274688;
    float* ctxbuf  = gpre;                      // alias (gpre dead after phase 2)
    float* ctx2buf = qbuf;                      // alias (qbuf dead after 3b)

    float* ws    = (float*)d_ws;
    float* t1buf = ws;                          // 16,777,216  [16384 x 1024]
    float* cws   = ws + 16777216;               //     32,768  [B,H]

    dim3 blk(256);

    // Phase 1: gate preactivations  gpre = concat(enc,cv) @ W_ih^T + b_ih + b_hh
    sgemm_kernel<1><<<dim3(G4_ / 128, 16384 / 128, 1), blk, 0, stream>>>(
        enc, cv, W_ih, b_ih, b_hh, gpre,
        16384, G4_, H_, H_, H2_, G4_, 0, 0, 0, 0);

    // Phase 2: sequential LSTM over t
    for (int t = 0; t < S_; t++) {
        const float* hp = t ? hall + (long)(t - 1) * H_ : h0;
        long hstr       = t ? (long)S_ * H_ : (long)H_;
        const float* cp = t ? (const float*)cws : c0;
        lstm_step_kernel<<<256, blk, 0, stream>>>(
            gpre, W_hh, hp, hstr, cp, cws, hall + (long)t * H_, t);
    }

    // Phase 3a: Q = hall @ attn_l1^T
    sgemm_kernel<1><<<dim3(H_ / 128, 16384 / 128, 1), blk, 0, stream>>>(
        hall, nullptr, al1, nullptr, nullptr, qbuf,
        16384, H_, H_, 0, H_, H_, 0, 0, 0, 0);

    // Phase 3b: scores[b,t,s] = Q[b,t,:] . enc[b,s,:]  (batched NT)
    sgemm_kernel<1><<<dim3(S_ / 128, S_ / 128, B_), blk, 0, stream>>>(
        qbuf, nullptr, enc, nullptr, nullptr, scoresb,
        S_, S_, H_, 0, H_, S_, (long)S_ * H_, (long)S_ * H_, (long)S_ * S_, 0);

    // Phase 3c: masked softmax over s
    masked_softmax_kernel<<<16384, blk, 0, stream>>>(scoresb, xs);

    // Phase 3d: ctx[b,t,:] = attn[b,t,:] @ enc[b]  (batched NN)
    sgemm_kernel<0><<<dim3(H_ / 128, S_ / 128, B_), blk, 0, stream>>>(
        scoresb, nullptr, enc, nullptr, nullptr, ctxbuf,
        S_, H_, S_, 0, H_, H_, (long)S_ * S_, (long)S_ * H_, (long)S_ * H_, 0);

    // Phase 3e: ctx2 = tanh(concat(ctx, hall) @ attn_l2^T)
    sgemm_kernel<1><<<dim3(H_ / 128, 16384 / 128, 1), blk, 0, stream>>>(
        ctxbuf, hall, al2, nullptr, nullptr, ctx2buf,
        16384, H_, H_, H_, H2_, H_, 0, 0, 0, 1);

    // Phase 3f: t1 = tanh(ctx2 @ lin1^T + lin1_b)
    sgemm_kernel<1><<<dim3(H_ / 128, 16384 / 128, 1), blk, 0, stream>>>(
        ctx2buf, nullptr, l1w, l1b, nullptr, t1buf,
        16384, H_, H_, 0, H_, H_, 0, 0, 0, 1);

    // Phase 3g: logits = t1 @ lin2^T + lin2_b  -> d_out (overwrites all scratch)
    sgemm_kernel<1><<<dim3(V_ / 128, 16384 / 128, 1), blk, 0, stream>>>(
        t1buf, nullptr, l2w, l2b, nullptr, out,
        16384, V_, H_, 0, H_, V_, 0, 0, 0, 0);

    // Phase 3h: in-place log_softmax over V
    log_softmax_kernel<<<16384, blk, 0, stream>>>(out);
}

// Round 10
// 15207.312 us; speedup vs baseline: 1.2387x; 1.2387x over previous
//
#include <hip/hip_runtime.h>
#include <math.h>

// Problem dims
#define B_  32
#define S_  512
#define H_  1024
#define V_  8192
#define G4_ 4096   // 4H
#define H2_ 2048   // 2H

// ---------------------------------------------------------------------------
// Generic fp32 GEMM (unchanged from validated baseline).
// ---------------------------------------------------------------------------
template<int TRANSB>
__global__ __launch_bounds__(256)
void sgemm_kernel(const float* __restrict__ A1, const float* __restrict__ A2,
                  const float* __restrict__ Bm,
                  const float* __restrict__ bias1, const float* __restrict__ bias2,
                  float* __restrict__ C,
                  int M, int N, int K1, int K2, int ldb, int ldc,
                  long sA, long sB, long sC, int act)
{
    __shared__ float As[16][132];
    __shared__ float Bs[16][132];
    const int tid = threadIdx.x;
    const int n0 = blockIdx.x * 128;
    const int m0 = blockIdx.y * 128;
    const int z  = blockIdx.z;
    const float* A1z = A1 + (long)z * sA;
    const float* A2z = A2;
    const float* Bz  = Bm + (long)z * sB;
    float*       Cz  = C  + (long)z * sC;

    const int K  = K1 + K2;
    const int tx = tid & 15, ty = tid >> 4;

    float acc[8][8];
#pragma unroll
    for (int i = 0; i < 8; i++)
#pragma unroll
        for (int j = 0; j < 8; j++) acc[i][j] = 0.f;

    for (int k0 = 0; k0 < K; k0 += 16) {
#pragma unroll
        for (int q = 0; q < 2; q++) {
            int L   = q * 256 + tid;
            int mm  = L >> 2;
            int kk4 = (L & 3) << 2;
            int gk  = k0 + kk4;
            float4 v;
            if (gk < K1) v = *(const float4*)(A1z + (long)(m0 + mm) * K1 + gk);
            else         v = *(const float4*)(A2z + (long)(m0 + mm) * K2 + (gk - K1));
            As[kk4 + 0][mm] = v.x; As[kk4 + 1][mm] = v.y;
            As[kk4 + 2][mm] = v.z; As[kk4 + 3][mm] = v.w;
        }
        if (TRANSB) {
#pragma unroll
            for (int q = 0; q < 2; q++) {
                int L   = q * 256 + tid;
                int nn  = L >> 2;
                int kk4 = (L & 3) << 2;
                float4 v = *(const float4*)(Bz + (long)(n0 + nn) * ldb + k0 + kk4);
                Bs[kk4 + 0][nn] = v.x; Bs[kk4 + 1][nn] = v.y;
                Bs[kk4 + 2][nn] = v.z; Bs[kk4 + 3][nn] = v.w;
            }
        } else {
#pragma unroll
            for (int q = 0; q < 2; q++) {
                int L   = q * 256 + tid;
                int kk  = L >> 5;
                int nn4 = (L & 31) << 2;
                float4 v = *(const float4*)(Bz + (long)(k0 + kk) * ldb + n0 + nn4);
                *(float4*)&Bs[kk][nn4] = v;
            }
        }
        __syncthreads();
#pragma unroll
        for (int kk = 0; kk < 16; kk++) {
            float a[8], b[8];
            *(float4*)&a[0] = *(const float4*)&As[kk][ty * 8];
            *(float4*)&a[4] = *(const float4*)&As[kk][ty * 8 + 4];
            *(float4*)&b[0] = *(const float4*)&Bs[kk][tx * 8];
            *(float4*)&b[4] = *(const float4*)&Bs[kk][tx * 8 + 4];
#pragma unroll
            for (int i = 0; i < 8; i++)
#pragma unroll
                for (int j = 0; j < 8; j++)
                    acc[i][j] = fmaf(a[i], b[j], acc[i][j]);
        }
        __syncthreads();
    }
#pragma unroll
    for (int i = 0; i < 8; i++) {
        long gm = m0 + ty * 8 + i;
#pragma unroll
        for (int j4 = 0; j4 < 2; j4++) {
            int gn = n0 + tx * 8 + j4 * 4;
            float4 v;
            v.x = acc[i][j4 * 4 + 0]; v.y = acc[i][j4 * 4 + 1];
            v.z = acc[i][j4 * 4 + 2]; v.w = acc[i][j4 * 4 + 3];
            if (bias1) { v.x += bias1[gn + 0]; v.y += bias1[gn + 1];
                         v.z += bias1[gn + 2]; v.w += bias1[gn + 3]; }
            if (bias2) { v.x += bias2[gn + 0]; v.y += bias2[gn + 1];
                         v.z += bias2[gn + 2]; v.w += bias2[gn + 3]; }
            if (act == 1) { v.x = tanhf(v.x); v.y = tanhf(v.y);
                            v.z = tanhf(v.z); v.w = tanhf(v.w); }
            *(float4*)(Cz + gm * ldc + gn) = v;
        }
    }
}

// ---------------------------------------------------------------------------
// bf16 MFMA GEMM:  C = act( concat(A1,A2) @ B^T + bias )
// A1:[M x K1], A2:[M x K2], B:[N x K] all row-major fp32 in memory; staged to
// LDS as bf16 (RNE), MFMA mfma_f32_16x16x32_bf16, fp32 accumulate.
// Tile 128x128, BK=32, 256 thr = 4 waves (2x2 grid of 64x64 per wave,
// each wave 4x4 fragments of 16x16). K1,K2 multiples of 32; M,N mult of 128.
// LDS rows padded to 40 bf16 (80B stride -> 2-way bank alias = free, m136).
// Fragment layout (m89-verified): A/B lane l holds row/col (l&15),
// k=(l>>4)*8..+8 contiguous; C/D: col=l&15, row=(l>>4)*4+reg.
// ---------------------------------------------------------------------------
typedef short v8s __attribute__((ext_vector_type(8)));
typedef float v4f __attribute__((ext_vector_type(4)));

__device__ __forceinline__ ushort f2bf(float x) {
    unsigned u = __float_as_uint(x);
    return (ushort)((u + 0x7FFFu + ((u >> 16) & 1u)) >> 16);   // RNE
}

__global__ __launch_bounds__(256)
void bgemm_nt_kernel(const float* __restrict__ A1, const float* __restrict__ A2,
                     const float* __restrict__ B,
                     const float* __restrict__ bias,
                     float* __restrict__ C,
                     int K1, int K2, int ldc, int act)
{
    constexpr int LDK = 40;
    __shared__ __align__(16) ushort As[128 * LDK];
    __shared__ __align__(16) ushort Bs[128 * LDK];
    const int tid = threadIdx.x;
    const int n0 = blockIdx.x * 128;
    const int m0 = blockIdx.y * 128;
    const int K  = K1 + K2;

    const int l  = tid & 63;
    const int w  = tid >> 6;
    const int wm = (w >> 1) * 64;       // wave row offset in tile
    const int wn = (w & 1) * 64;        // wave col offset
    const int fr = l & 15;              // fragment row/col
    const int ko = (l >> 4) * 8;        // fragment k offset

    const int srow = tid >> 3;          // staging: 0..31
    const int skc  = (tid & 7) * 4;     // staging k: 0,4,...,28

    v4f acc[4][4];
#pragma unroll
    for (int i = 0; i < 4; i++)
#pragma unroll
        for (int j = 0; j < 4; j++)
#pragma unroll
            for (int r = 0; r < 4; r++) acc[i][j][r] = 0.f;

    for (int k0 = 0; k0 < K; k0 += 32) {
        // BK=32 divides K1, so a K-tile never straddles the concat boundary.
        const float* Az; int kb, lda;
        if (k0 < K1) { Az = A1; kb = k0;      lda = K1; }
        else         { Az = A2; kb = k0 - K1; lda = K2; }
#pragma unroll
        for (int p = 0; p < 4; p++) {
            int r = srow + p * 32;
            float4 va = *(const float4*)(Az + (long)(m0 + r) * lda + kb + skc);
            ushort4 pa;
            pa.x = f2bf(va.x); pa.y = f2bf(va.y); pa.z = f2bf(va.z); pa.w = f2bf(va.w);
            *(ushort4*)&As[r * LDK + skc] = pa;
            float4 vb = *(const float4*)(B + (long)(n0 + r) * K + k0 + skc);
            ushort4 pb;
            pb.x = f2bf(vb.x); pb.y = f2bf(vb.y); pb.z = f2bf(vb.z); pb.w = f2bf(vb.w);
            *(ushort4*)&Bs[r * LDK + skc] = pb;
        }
        __syncthreads();
        v8s av[4], bv[4];
#pragma unroll
        for (int i = 0; i < 4; i++)
            av[i] = *(const v8s*)&As[(wm + i * 16 + fr) * LDK + ko];
#pragma unroll
        for (int j = 0; j < 4; j++)
            bv[j] = *(const v8s*)&Bs[(wn + j * 16 + fr) * LDK + ko];
#pragma unroll
        for (int i = 0; i < 4; i++)
#pragma unroll
            for (int j = 0; j < 4; j++)
                acc[i][j] = __builtin_amdgcn_mfma_f32_16x16x32_bf16(
                    av[i], bv[j], acc[i][j], 0, 0, 0);
        __syncthreads();
    }

    const int orow = (l >> 4) * 4;
#pragma unroll
    for (int i = 0; i < 4; i++) {
#pragma unroll
        for (int j = 0; j < 4; j++) {
            int col = n0 + wn + j * 16 + fr;
            float bb = bias ? bias[col] : 0.f;
#pragma unroll
            for (int r = 0; r < 4; r++) {
                long row = m0 + wm + i * 16 + orow + r;
                float v = acc[i][j][r] + bb;
                if (act == 1) v = tanhf(v);
                C[row * (long)ldc + col] = v;
            }
        }
    }
}

// ---------------------------------------------------------------------------
// One LSTM step (unchanged from validated baseline).
// ---------------------------------------------------------------------------
__global__ __launch_bounds__(256, 1)
void lstm_step_kernel(const float* __restrict__ gpre, const float* __restrict__ Whh,
                      const float* __restrict__ hprev, long hstride,
                      const float* __restrict__ cprev,
                      float* __restrict__ cnext, float* __restrict__ hall_t,
                      int t)
{
    __shared__ float hs[64 * 132];
    const int tid = threadIdx.x;
    const int bid = blockIdx.x;
    const int rr  = tid & 3;
    const int c   = tid >> 2;

    float wreg[4][16];
#pragma unroll
    for (int m = 0; m < 4; m++) {
        const float* wr = Whh + (long)(rr * 1024 + bid * 4 + m) * 1024;
#pragma unroll
        for (int q = 0; q < 4; q++) {
            float4 v = *(const float4*)(wr + q * 256 + c * 4);
            wreg[m][q * 4 + 0] = v.x; wreg[m][q * 4 + 1] = v.y;
            wreg[m][q * 4 + 2] = v.z; wreg[m][q * 4 + 3] = v.w;
        }
    }

    float acc[4][32];
#pragma unroll
    for (int m = 0; m < 4; m++)
#pragma unroll
        for (int b = 0; b < 32; b++) acc[m][b] = 0.f;

#pragma unroll
    for (int q = 0; q < 4; q++) {
        {
            int g  = tid & 63;
            int bq = tid >> 6;
#pragma unroll
            for (int v4 = 0; v4 < 8; v4++) {
                int b = bq * 8 + v4;
                float4 v = *(const float4*)(hprev + (long)b * hstride + q * 256 + g * 4);
                *(float4*)&hs[g * 132 + b * 4] = v;
            }
        }
        __syncthreads();
#pragma unroll
        for (int b = 0; b < 32; b++) {
            float4 h4 = *(const float4*)&hs[c * 132 + b * 4];
#pragma unroll
            for (int m = 0; m < 4; m++) {
                acc[m][b] = fmaf(wreg[m][q * 4 + 0], h4.x, acc[m][b]);
                acc[m][b] = fmaf(wreg[m][q * 4 + 1], h4.y, acc[m][b]);
                acc[m][b] = fmaf(wreg[m][q * 4 + 2], h4.z, acc[m][b]);
                acc[m][b] = fmaf(wreg[m][q * 4 + 3], h4.w, acc[m][b]);
            }
        }
        __syncthreads();
    }

#pragma unroll
    for (int m = 0; m < 4; m++)
#pragma unroll
        for (int b = 0; b < 32; b++) {
            float v = acc[m][b];
            v += __shfl_xor(v, 4);
            v += __shfl_xor(v, 8);
            v += __shfl_xor(v, 16);
            v += __shfl_xor(v, 32);
            acc[m][b] = v;
        }

    int w = tid >> 6;
    if ((tid & 63) < 4) {
        int r2 = tid & 3;
#pragma unroll
        for (int m = 0; m < 4; m++)
#pragma unroll
            for (int b = 0; b < 32; b++)
                hs[(w * 16 + r2 * 4 + m) * 33 + b] = acc[m][b];
    }
    __syncthreads();

    if (tid < 128) {
        int jj = tid >> 5;
        int b  = tid & 31;
        float gv[4];
#pragma unroll
        for (int g = 0; g < 4; g++) {
            int lr = g * 4 + jj;
            float s = hs[(0 * 16 + lr) * 33 + b] + hs[(1 * 16 + lr) * 33 + b]
                    + hs[(2 * 16 + lr) * 33 + b] + hs[(3 * 16 + lr) * 33 + b];
            gv[g] = s + gpre[((long)b * S_ + t) * G4_ + g * H_ + bid * 4 + jj];
        }
        int col = bid * 4 + jj;
        float cp = cprev[b * H_ + col];
        float ig = 1.f / (1.f + expf(-gv[0]));
        float fg = 1.f / (1.f + expf(-gv[1]));
        float gg = tanhf(gv[2]);
        float og = 1.f / (1.f + expf(-gv[3]));
        float cn = fg * cp + ig * gg;
        float hn = og * tanhf(cn);
        cnext[b * H_ + col] = cn;
        hall_t[(long)b * (S_ * H_) + col] = hn;
    }
}

// ---------------------------------------------------------------------------
// reductions (unchanged)
// ---------------------------------------------------------------------------
__device__ __forceinline__ float wave_max(float v) {
    v = fmaxf(v, __shfl_xor(v, 1));  v = fmaxf(v, __shfl_xor(v, 2));
    v = fmaxf(v, __shfl_xor(v, 4));  v = fmaxf(v, __shfl_xor(v, 8));
    v = fmaxf(v, __shfl_xor(v, 16)); v = fmaxf(v, __shfl_xor(v, 32));
    return v;
}
__device__ __forceinline__ float wave_sum(float v) {
    v += __shfl_xor(v, 1);  v += __shfl_xor(v, 2);
    v += __shfl_xor(v, 4);  v += __shfl_xor(v, 8);
    v += __shfl_xor(v, 16); v += __shfl_xor(v, 32);
    return v;
}

__global__ __launch_bounds__(256)
void masked_softmax_kernel(float* __restrict__ sc, const int* __restrict__ xs)
{
    __shared__ float red[4];
    int row = blockIdx.x;
    int b   = row >> 9;
    int len = xs[b];
    float* p = sc + (long)row * S_;
    int tid = threadIdx.x;
    float v0 = p[tid];
    float v1 = p[tid + 256];
    v0 = (tid < len) ? v0 : 0.f;       if (v0 == 0.f) v0 = -1e10f;
    v1 = (tid + 256 < len) ? v1 : 0.f; if (v1 == 0.f) v1 = -1e10f;
    float m = wave_max(fmaxf(v0, v1));
    if ((tid & 63) == 0) red[tid >> 6] = m;
    __syncthreads();
    m = fmaxf(fmaxf(red[0], red[1]), fmaxf(red[2], red[3]));
    float e0 = expf(v0 - m), e1 = expf(v1 - m);
    float s = wave_sum(e0 + e1);
    __syncthreads();
    if ((tid & 63) == 0) red[tid >> 6] = s;
    __syncthreads();
    s = red[0] + red[1] + red[2] + red[3];
    float inv = 1.f / s;
    p[tid] = e0 * inv;
    p[tid + 256] = e1 * inv;
}

__global__ __launch_bounds__(256)
void log_softmax_kernel(float* __restrict__ out)
{
    __shared__ float red[4];
    long row = blockIdx.x;
    float* p = out + row * V_;
    int tid = threadIdx.x;
    float x[32];
#pragma unroll
    for (int i = 0; i < 8; i++)
        *(float4*)&x[i * 4] = *(const float4*)(p + i * 1024 + tid * 4);
    float m = -INFINITY;
#pragma unroll
    for (int i = 0; i < 32; i++) m = fmaxf(m, x[i]);
    m = wave_max(m);
    if ((tid & 63) == 0) red[tid >> 6] = m;
    __syncthreads();
    m = fmaxf(fmaxf(red[0], red[1]), fmaxf(red[2], red[3]));
    float s = 0.f;
#pragma unroll
    for (int i = 0; i < 32; i++) s += expf(x[i] - m);
    s = wave_sum(s);
    __syncthreads();
    if ((tid & 63) == 0) red[tid >> 6] = s;
    __syncthreads();
    s = red[0] + red[1] + red[2] + red[3];
    float lse = m + logf(s);
#pragma unroll
    for (int i = 0; i < 8; i++) {
        float4 v;
        v.x = x[i * 4 + 0] - lse; v.y = x[i * 4 + 1] - lse;
        v.z = x[i * 4 + 2] - lse; v.w = x[i * 4 + 3] - lse;
        *(float4*)(p + i * 1024 + tid * 4) = v;
    }
}

// ---------------------------------------------------------------------------
extern "C" void kernel_launch(void* const* d_in, const int* in_sizes, int n_in,
                              void* d_out, int out_size, void* d_ws, size_t ws_size,
                              hipStream_t stream)
{
    const float* enc  = (const float*)d_in[0];
    const float* h0   = (const float*)d_in[1];
    const float* c0   = (const float*)d_in[2];
    const float* cv   = (const float*)d_in[3];
    const float* W_ih = (const float*)d_in[4];
    const float* b_ih = (const float*)d_in[5];
    const float* W_hh = (const float*)d_in[6];
    const float* b_hh = (const float*)d_in[7];
    const float* al1  = (const float*)d_in[8];
    const float* al2  = (const float*)d_in[9];
    const float* l1w  = (const float*)d_in[10];
    const float* l1b  = (const float*)d_in[11];
    const float* l2w  = (const float*)d_in[12];
    const float* l2b  = (const float*)d_in[13];
    const int*   xs   = (const int*)d_in[14];
    float* out = (float*)d_out;

    // scratch carve (validated r6): d_out is scratch until 3g overwrites it.
    float* gpre    = out;
    float* qbuf    = out + 67108864;
    float* scoresb = out + 83886080;
    float* hall    = out + 92274688;
    float* ctxbuf  = gpre;                      // alias (gpre dead after phase 2)
    float* ctx2buf = qbuf;                      // alias (qbuf dead after 3b)

    float* ws    = (float*)d_ws;
    float* t1buf = ws;                          // survives 3g
    float* cws   = ws + 16777216;

    dim3 blk(256);

    // Phase 1 (fp32 — precision-critical, feeds recurrence)
    sgemm_kernel<1><<<dim3(G4_ / 128, 16384 / 128, 1), blk, 0, stream>>>(
        enc, cv, W_ih, b_ih, b_hh, gpre,
        16384, G4_, H_, H_, H2_, G4_, 0, 0, 0, 0);

    // Phase 2 (fp32, unchanged)
    for (int t = 0; t < S_; t++) {
        const float* hp = t ? hall + (long)(t - 1) * H_ : h0;
        long hstr       = t ? (long)S_ * H_ : (long)H_;
        const float* cp = t ? (const float*)cws : c0;
        lstm_step_kernel<<<256, blk, 0, stream>>>(
            gpre, W_hh, hp, hstr, cp, cws, hall + (long)t * H_, t);
    }

    // Phase 3a: Q = hall @ attn_l1^T  (fp32 — feeds score softmax)
    sgemm_kernel<1><<<dim3(H_ / 128, 16384 / 128, 1), blk, 0, stream>>>(
        hall, nullptr, al1, nullptr, nullptr, qbuf,
        16384, H_, H_, 0, H_, H_, 0, 0, 0, 0);

    // Phase 3b: scores (fp32 — exp-amplified)
    sgemm_kernel<1><<<dim3(S_ / 128, S_ / 128, B_), blk, 0, stream>>>(
        qbuf, nullptr, enc, nullptr, nullptr, scoresb,
        S_, S_, H_, 0, H_, S_, (long)S_ * H_, (long)S_ * H_, (long)S_ * S_, 0);

    // Phase 3c: masked softmax
    masked_softmax_kernel<<<16384, blk, 0, stream>>>(scoresb, xs);

    // Phase 3d: ctx = attn @ enc  (fp32, NN, small)
    sgemm_kernel<0><<<dim3(H_ / 128, S_ / 128, B_), blk, 0, stream>>>(
        scoresb, nullptr, enc, nullptr, nullptr, ctxbuf,
        S_, H_, S_, 0, H_, H_, (long)S_ * S_, (long)S_ * H_, (long)S_ * H_, 0);

    // Phase 3e: ctx2 = tanh(concat(ctx, hall) @ al2^T)   [bf16 MFMA]
    bgemm_nt_kernel<<<dim3(H_ / 128, 16384 / 128), blk, 0, stream>>>(
        ctxbuf, hall, al2, nullptr, ctx2buf, H_, H_, H_, 1);

    // Phase 3f: t1 = tanh(ctx2 @ l1w^T + l1b)            [bf16 MFMA]
    bgemm_nt_kernel<<<dim3(H_ / 128, 16384 / 128), blk, 0, stream>>>(
        ctx2buf, nullptr, l1w, l1b, t1buf, H_, 0, H_, 1);

    // Phase 3g: logits = t1 @ l2w^T + l2b -> d_out       [bf16 MFMA]
    bgemm_nt_kernel<<<dim3(V_ / 128, 16384 / 128), blk, 0, stream>>>(
        t1buf, nullptr, l2w, l2b, out, H_, 0, V_, 0);

    // Phase 3h: log_softmax in place
    log_softmax_kernel<<<16384, blk, 0, stream>>>(out);
}